// Round 3
// baseline (1381.012 us; speedup 1.0000x reference)
//
#include <hip/hip_runtime.h>

#define N_NODES 100000
#define N_EDGES 1600000
#define D_IN 128
#define HID 64
#define N_LAYERS 5
#define D_OUT 32
#define N_GRAPHS 1000

#define LNB 32            // nodes per block in k_layer (4 waves x 8)
#define LR 8              // nodes per wave

__device__ __forceinline__ float fast_sigmoid(float x) {
    return __builtin_amdgcn_rcpf(1.0f + __expf(-x));
}
__device__ __forceinline__ float fast_tanh(float x) {
    return 1.0f - 2.0f * __builtin_amdgcn_rcpf(1.0f + __expf(2.0f * x));
}

// ---------------------------------------------------------------------------
// Weight prep. Output layout (float index):
//   W4[(((l*16 + k4)*6 + g)*64 + j)*4 + kk]
// g 0..2: combined input-side weights  Wc[k][g*64+j] = sum_q ggnn_w[l][k][q]*w_ih[(g*64+j)][q]
// g 3..5: hidden-side transpose        w_hh[(g-3)*64+j][k]
// where k = k4*4+kk.  One wave-load of float4 at lane j gives 4 consecutive k.
__global__ void k_prep(const float* __restrict__ ggnn_w,
                       const float* __restrict__ w_ih,
                       const float* __restrict__ w_hh,
                       float* __restrict__ W4) {
    int t = blockIdx.x * blockDim.x + threadIdx.x;
    if (t >= N_LAYERS * 16 * 6 * 64 * 4) return;
    int rem = t;
    int kk = rem & 3;  rem >>= 2;
    int j  = rem & 63; rem >>= 6;
    int g  = rem % 6;  rem /= 6;
    int k4 = rem & 15;
    int l  = rem >> 4;
    int k  = k4 * 4 + kk;
    float v;
    if (g < 3) {
        const float* wl = ggnn_w + ((size_t)l * HID + k) * HID;
        const float* wi = w_ih + (size_t)(g * 64 + j) * HID;
        float acc = 0.0f;
#pragma unroll 8
        for (int q = 0; q < HID; ++q) acc = fmaf(wl[q], wi[q], acc);
        v = acc;
    } else {
        v = w_hh[(size_t)((g - 3) * 64 + j) * HID + k];
    }
    W4[t] = v;
}

// ---------------------------------------------------------------------------
// CSR build. hist returns the slot -> no second atomic pass.
__global__ void k_hist(const int* __restrict__ ei,
                       int* __restrict__ deg,
                       int* __restrict__ eslot) {
    int e = blockIdx.x * blockDim.x + threadIdx.x;
    if (e >= N_EDGES) return;
    eslot[e] = atomicAdd(&deg[ei[N_EDGES + e]], 1);
}

#define SCHUNK 1024
__global__ __launch_bounds__(1024) void k_scan1(const int* __restrict__ deg,
                                                int* __restrict__ off,
                                                int* __restrict__ bsum) {
    __shared__ int buf[SCHUNK];
    int tid = threadIdx.x;
    int i = blockIdx.x * SCHUNK + tid;
    int v = (i < N_NODES) ? deg[i] : 0;
    buf[tid] = v;
    __syncthreads();
    for (int s = 1; s < SCHUNK; s <<= 1) {
        int a = (tid >= s) ? buf[tid - s] : 0;
        __syncthreads();
        buf[tid] += a;
        __syncthreads();
    }
    if (i < N_NODES) off[i] = buf[tid] - v;
    if (tid == SCHUNK - 1) bsum[blockIdx.x] = buf[tid];
}

__global__ void k_scan2(int* __restrict__ bsum, int* __restrict__ off, int nchunks) {
    if (blockIdx.x == 0 && threadIdx.x == 0) {
        int carry = 0;
        for (int b = 0; b < nchunks; ++b) {
            int t = bsum[b];
            bsum[b] = carry;
            carry += t;
        }
        off[N_NODES] = carry;
    }
}

__global__ void k_scan3(int* __restrict__ off, const int* __restrict__ bsum) {
    int i = blockIdx.x * blockDim.x + threadIdx.x;
    if (i < N_NODES) off[i] += bsum[i >> 10];
}

__global__ void k_place(const int* __restrict__ ei,
                        const int* __restrict__ off,
                        const int* __restrict__ eslot,
                        int* __restrict__ csr) {
    int e = blockIdx.x * blockDim.x + threadIdx.x;
    if (e >= N_EDGES) return;
    int d = ei[N_EDGES + e];
    csr[off[d] + eslot[e]] = ei[e];
}

// ---------------------------------------------------------------------------
// x = node_embed @ W_in + b_in,  8 nodes/thread, rows staged in LDS
__global__ __launch_bounds__(256) void k_input(const float* __restrict__ ne,
                                               const float* __restrict__ W_in,
                                               const float* __restrict__ b_in,
                                               float* __restrict__ h) {
    __shared__ float sE[LNB][D_IN];            // 16 KB
    int tid = threadIdx.x;
    int j = tid & 63, w = tid >> 6;
    int nodeBase = blockIdx.x * LNB;
    {
        const float4* g = (const float4*)(ne + (size_t)nodeBase * D_IN);
        float4* l = (float4*)&sE[0][0];
        for (int i = tid; i < LNB * D_IN / 4; i += 256) l[i] = g[i];
    }
    __syncthreads();
    float acc[LR];
#pragma unroll
    for (int r = 0; r < LR; ++r) acc[r] = 0.0f;
#pragma unroll 4
    for (int k = 0; k < D_IN; ++k) {
        float wv = W_in[k * HID + j];
#pragma unroll
        for (int r = 0; r < LR; ++r)
            acc[r] = fmaf(sE[w * LR + r][k], wv, acc[r]);
    }
    float b = b_in[j];
#pragma unroll
    for (int r = 0; r < LR; ++r) {
        int n = nodeBase + w * LR + r;
        h[(size_t)n * HID + j] = acc[r] + b;
    }
}

// ---------------------------------------------------------------------------
// Fused layer: CSR gather (vectorized 4 rows/wave-load) + GRU update.
// Reads h_old everywhere, writes h_new (double buffer -> no race).
__global__ __launch_bounds__(256) void k_layer(const int* __restrict__ off,
                                               const int* __restrict__ csr,
                                               const float* __restrict__ h_old,
                                               float* __restrict__ h_new,
                                               const float* __restrict__ W4f,
                                               const float* __restrict__ b_ih,
                                               const float* __restrict__ b_hh) {
    __shared__ float sA[LNB][HID];             // 8 KB  (aggregated messages)
    __shared__ float sH[LNB][HID];             // 8 KB  (own h rows)
    int tid = threadIdx.x;
    int lane = tid & 63, w = tid >> 6;         // w: 0..3
    int nodeBase = blockIdx.x * LNB;

    // stage own 32 rows coalesced (8 KB)
    {
        const float4* g4 = (const float4*)(h_old + (size_t)nodeBase * HID);
        float4* l4 = (float4*)&sH[0][0];
#pragma unroll
        for (int i = 0; i < 2; ++i) l4[tid + i * 256] = g4[tid + i * 256];
    }

    // gather: wave w handles nodes w*8 .. w*8+7; 4 neighbor rows per wave-load
    int q = lane >> 4, c = lane & 15;
#pragma unroll
    for (int r = 0; r < LR; ++r) {
        int n = nodeBase + w * LR + r;
        int beg = off[n], end = off[n + 1];
        float ax = 0.f, ay = 0.f, az = 0.f, aw = 0.f;
        for (int i = beg + q; i < end; i += 4) {
            const float4 v = *(const float4*)(h_old + (size_t)csr[i] * HID + c * 4);
            ax += v.x; ay += v.y; az += v.z; aw += v.w;
        }
        ax += __shfl_xor(ax, 16); ay += __shfl_xor(ay, 16);
        az += __shfl_xor(az, 16); aw += __shfl_xor(aw, 16);
        ax += __shfl_xor(ax, 32); ay += __shfl_xor(ay, 32);
        az += __shfl_xor(az, 32); aw += __shfl_xor(aw, 32);
        if (q == 0) {
            float4 t4; t4.x = ax; t4.y = ay; t4.z = az; t4.w = aw;
            *(float4*)&sA[w * LR + r][c * 4] = t4;
        }
    }
    __syncthreads();

    // GRU: lane = output feature j, 8 nodes per thread
    int j = lane;
    float air[LR], aiz[LR], ain[LR], ahr[LR], ahz[LR], ahn[LR];
#pragma unroll
    for (int r = 0; r < LR; ++r) {
        air[r] = 0.f; aiz[r] = 0.f; ain[r] = 0.f;
        ahr[r] = 0.f; ahz[r] = 0.f; ahn[r] = 0.f;
    }
    const float4* W = (const float4*)W4f;
    for (int k4 = 0; k4 < 16; ++k4) {
        float4 wir = W[(k4 * 6 + 0) * 64 + j];
        float4 wiz = W[(k4 * 6 + 1) * 64 + j];
        float4 win = W[(k4 * 6 + 2) * 64 + j];
        float4 whr = W[(k4 * 6 + 3) * 64 + j];
        float4 whz = W[(k4 * 6 + 4) * 64 + j];
        float4 whn = W[(k4 * 6 + 5) * 64 + j];
#pragma unroll
        for (int r = 0; r < LR; ++r) {
            float4 a4 = *(const float4*)&sA[w * LR + r][k4 * 4];
            float4 h4 = *(const float4*)&sH[w * LR + r][k4 * 4];
            air[r] = fmaf(a4.x, wir.x, air[r]); air[r] = fmaf(a4.y, wir.y, air[r]);
            air[r] = fmaf(a4.z, wir.z, air[r]); air[r] = fmaf(a4.w, wir.w, air[r]);
            aiz[r] = fmaf(a4.x, wiz.x, aiz[r]); aiz[r] = fmaf(a4.y, wiz.y, aiz[r]);
            aiz[r] = fmaf(a4.z, wiz.z, aiz[r]); aiz[r] = fmaf(a4.w, wiz.w, aiz[r]);
            ain[r] = fmaf(a4.x, win.x, ain[r]); ain[r] = fmaf(a4.y, win.y, ain[r]);
            ain[r] = fmaf(a4.z, win.z, ain[r]); ain[r] = fmaf(a4.w, win.w, ain[r]);
            ahr[r] = fmaf(h4.x, whr.x, ahr[r]); ahr[r] = fmaf(h4.y, whr.y, ahr[r]);
            ahr[r] = fmaf(h4.z, whr.z, ahr[r]); ahr[r] = fmaf(h4.w, whr.w, ahr[r]);
            ahz[r] = fmaf(h4.x, whz.x, ahz[r]); ahz[r] = fmaf(h4.y, whz.y, ahz[r]);
            ahz[r] = fmaf(h4.z, whz.z, ahz[r]); ahz[r] = fmaf(h4.w, whz.w, ahz[r]);
            ahn[r] = fmaf(h4.x, whn.x, ahn[r]); ahn[r] = fmaf(h4.y, whn.y, ahn[r]);
            ahn[r] = fmaf(h4.z, whn.z, ahn[r]); ahn[r] = fmaf(h4.w, whn.w, ahn[r]);
        }
    }
    float bir = b_ih[j], biz = b_ih[64 + j], bin_ = b_ih[128 + j];
    float bhr = b_hh[j], bhz = b_hh[64 + j], bhn = b_hh[128 + j];
#pragma unroll
    for (int r = 0; r < LR; ++r) {
        int nn = w * LR + r;
        float rr = fast_sigmoid((air[r] + bir) + (ahr[r] + bhr));
        float zz = fast_sigmoid((aiz[r] + biz) + (ahz[r] + bhz));
        float nv = fast_tanh((ain[r] + bin_) + rr * (ahn[r] + bhn));
        float hold = sH[nn][j];
        h_new[(size_t)(nodeBase + nn) * HID + j] = (1.0f - zz) * nv + zz * hold;
    }
}

// ---------------------------------------------------------------------------
#define POOL_NPW 64
__global__ void k_pool(const float* __restrict__ h,
                       const int* __restrict__ batch,
                       float* __restrict__ sums,
                       float* __restrict__ cntf) {
    int wid = (blockIdx.x * blockDim.x + threadIdx.x) >> 6;
    int j = threadIdx.x & 63;
    int base = wid * POOL_NPW;
    if (base >= N_NODES) return;
    int end = base + POOL_NPW;
    if (end > N_NODES) end = N_NODES;
    float acc = 0.f, c = 0.f;
    int curg = batch[base];
    for (int n = base; n < end; ++n) {
        int g = batch[n];
        if (g != curg) {
            atomicAdd(&sums[(size_t)curg * HID + j], acc);
            if (j == 0) atomicAdd(&cntf[curg], c);
            acc = 0.f; c = 0.f; curg = g;
        }
        acc += h[(size_t)n * HID + j];
        c += 1.f;
    }
    atomicAdd(&sums[(size_t)curg * HID + j], acc);
    if (j == 0) atomicAdd(&cntf[curg], c);
}

__global__ void k_out(const float* __restrict__ sums,
                      const float* __restrict__ cntf,
                      const float* __restrict__ W_out,
                      const float* __restrict__ b_out,
                      float* __restrict__ out) {
    int t = blockIdx.x * blockDim.x + threadIdx.x;
    if (t >= N_GRAPHS * D_OUT) return;
    int g = t / D_OUT, o = t % D_OUT;
    float inv_c = __builtin_amdgcn_rcpf(fmaxf(cntf[g], 1.0f));
    float acc = 0.0f;
#pragma unroll
    for (int k = 0; k < HID; ++k)
        acc = fmaf(sums[g * HID + k], W_out[k * D_OUT + o], acc);
    out[t] = acc * inv_c + b_out[o];
}

// ---------------------------------------------------------------------------
static inline char* align256(char* p) {
    return (char*)(((uintptr_t)p + 255) & ~(uintptr_t)255);
}

extern "C" void kernel_launch(void* const* d_in, const int* in_sizes, int n_in,
                              void* d_out, int out_size, void* d_ws, size_t ws_size,
                              hipStream_t stream) {
    const float* node_embed = (const float*)d_in[0];
    const int*   edge_index = (const int*)  d_in[1];
    const int*   batch      = (const int*)  d_in[2];
    const float* W_in       = (const float*)d_in[3];
    const float* b_in       = (const float*)d_in[4];
    const float* ggnn_w     = (const float*)d_in[5];
    const float* gru_w_ih   = (const float*)d_in[6];
    const float* gru_w_hh   = (const float*)d_in[7];
    const float* gru_b_ih   = (const float*)d_in[8];
    const float* gru_b_hh   = (const float*)d_in[9];
    const float* W_out      = (const float*)d_in[10];
    const float* b_out      = (const float*)d_in[11];
    float* out = (float*)d_out;

    char* p = (char*)d_ws;
    float* h0    = (float*)p; p = align256(p + (size_t)N_NODES * HID * sizeof(float));
    float* h1    = (float*)p; p = align256(p + (size_t)N_NODES * HID * sizeof(float));
    int*   csr   = (int*)  p; p = align256(p + (size_t)N_EDGES * sizeof(int));
    int*   eslot = (int*)  p; p = align256(p + (size_t)N_EDGES * sizeof(int));
    int*   off   = (int*)  p; p = align256(p + (size_t)(N_NODES + 1) * sizeof(int));
    int*   deg   = (int*)  p; p = align256(p + (size_t)N_NODES * sizeof(int));
    int*   bsum  = (int*)  p; p = align256(p + 256 * sizeof(int));
    float* W4    = (float*)p; p = align256(p + (size_t)N_LAYERS * 16 * 6 * 64 * 4 * sizeof(float));
    float* sums  = (float*)p;
    float* cntf  = (float*)(p + (size_t)N_GRAPHS * HID * sizeof(float));

    const int BLK = 256;
    const int nchunks = (N_NODES + SCHUNK - 1) / SCHUNK;

    // weight prep
    k_prep<<<(N_LAYERS * 16 * 6 * 64 * 4 + BLK - 1) / BLK, BLK, 0, stream>>>(
        ggnn_w, gru_w_ih, gru_w_hh, W4);

    // CSR build
    hipMemsetAsync(deg, 0, (size_t)N_NODES * sizeof(int), stream);
    k_hist<<<(N_EDGES + BLK - 1) / BLK, BLK, 0, stream>>>(edge_index, deg, eslot);
    k_scan1<<<nchunks, SCHUNK, 0, stream>>>(deg, off, bsum);
    k_scan2<<<1, 64, 0, stream>>>(bsum, off, nchunks);
    k_scan3<<<(N_NODES + BLK - 1) / BLK, BLK, 0, stream>>>(off, bsum);
    k_place<<<(N_EDGES + BLK - 1) / BLK, BLK, 0, stream>>>(edge_index, off, eslot, csr);

    // input linear
    k_input<<<N_NODES / LNB, BLK, 0, stream>>>(node_embed, W_in, b_in, h0);

    // 5 fused GGNN layers, ping-pong h0/h1
    float* hin = h0;
    float* hout = h1;
    for (int l = 0; l < N_LAYERS; ++l) {
        k_layer<<<N_NODES / LNB, BLK, 0, stream>>>(
            off, csr, hin, hout, W4 + (size_t)l * 16 * 6 * 64 * 4, gru_b_ih, gru_b_hh);
        float* t = hin; hin = hout; hout = t;
    }
    // after 5 layers the final h is in `hin`

    hipMemsetAsync(sums, 0, (size_t)N_GRAPHS * (HID + 1) * sizeof(float), stream);
    {
        int waves = (N_NODES + POOL_NPW - 1) / POOL_NPW;
        int threads = waves * 64;
        k_pool<<<(threads + BLK - 1) / BLK, BLK, 0, stream>>>(hin, batch, sums, cntf);
    }
    k_out<<<(N_GRAPHS * D_OUT + BLK - 1) / BLK, BLK, 0, stream>>>(sums, cntf, W_out, b_out, out);
}

// Round 4
// 1128.530 us; speedup vs baseline: 1.2237x; 1.2237x over previous
//
#include <hip/hip_runtime.h>

#define N_NODES 100000
#define N_EDGES 1600000
#define D_IN 128
#define HID 64
#define N_LAYERS 5
#define D_OUT 32
#define N_GRAPHS 1000

#define LNB 32            // nodes per block in k_gru/k_input (4 waves x 8)
#define LR 8              // nodes per thread

typedef unsigned short ushort_t;
typedef unsigned int uint_t;

__device__ __forceinline__ float fast_sigmoid(float x) {
    return __builtin_amdgcn_rcpf(1.0f + __expf(-x));
}
__device__ __forceinline__ float fast_tanh(float x) {
    return 1.0f - 2.0f * __builtin_amdgcn_rcpf(1.0f + __expf(2.0f * x));
}
// fp32 -> bf16 with round-to-nearest-even
__device__ __forceinline__ ushort_t f2bf(float f) {
    uint_t u = __float_as_uint(f);
    return (ushort_t)((u + 0x7fffu + ((u >> 16) & 1u)) >> 16);
}

// ---------------------------------------------------------------------------
// Weight prep. Output layout (float index):
//   W4[(((l*16 + k4)*6 + g)*64 + j)*4 + kk]
// g 0..2: combined input-side  Wc[k][g*64+j] = sum_q ggnn_w[l][k][q]*w_ih[g*64+j][q]
// g 3..5: hidden-side transpose w_hh[(g-3)*64+j][k],  k = k4*4+kk
__global__ void k_prep(const float* __restrict__ ggnn_w,
                       const float* __restrict__ w_ih,
                       const float* __restrict__ w_hh,
                       float* __restrict__ W4) {
    int t = blockIdx.x * blockDim.x + threadIdx.x;
    if (t >= N_LAYERS * 16 * 6 * 64 * 4) return;
    int rem = t;
    int kk = rem & 3;  rem >>= 2;
    int j  = rem & 63; rem >>= 6;
    int g  = rem % 6;  rem /= 6;
    int k4 = rem & 15;
    int l  = rem >> 4;
    int k  = k4 * 4 + kk;
    float v;
    if (g < 3) {
        const float* wl = ggnn_w + ((size_t)l * HID + k) * HID;
        const float* wi = w_ih + (size_t)(g * 64 + j) * HID;
        float acc = 0.0f;
#pragma unroll 8
        for (int q = 0; q < HID; ++q) acc = fmaf(wl[q], wi[q], acc);
        v = acc;
    } else {
        v = w_hh[(size_t)((g - 3) * 64 + j) * HID + k];
    }
    W4[t] = v;
}

// ---------------------------------------------------------------------------
// CSR build
__global__ void k_hist(const int* __restrict__ ei,
                       int* __restrict__ deg,
                       int* __restrict__ eslot) {
    int e = blockIdx.x * blockDim.x + threadIdx.x;
    if (e >= N_EDGES) return;
    eslot[e] = atomicAdd(&deg[ei[N_EDGES + e]], 1);
}

#define SCHUNK 1024
__global__ __launch_bounds__(1024) void k_scan1(const int* __restrict__ deg,
                                                int* __restrict__ off,
                                                int* __restrict__ bsum) {
    __shared__ int buf[SCHUNK];
    int tid = threadIdx.x;
    int i = blockIdx.x * SCHUNK + tid;
    int v = (i < N_NODES) ? deg[i] : 0;
    buf[tid] = v;
    __syncthreads();
    for (int s = 1; s < SCHUNK; s <<= 1) {
        int a = (tid >= s) ? buf[tid - s] : 0;
        __syncthreads();
        buf[tid] += a;
        __syncthreads();
    }
    if (i < N_NODES) off[i] = buf[tid] - v;
    if (tid == SCHUNK - 1) bsum[blockIdx.x] = buf[tid];
}

__global__ void k_scan2(int* __restrict__ bsum, int* __restrict__ off, int nchunks) {
    if (blockIdx.x == 0 && threadIdx.x == 0) {
        int carry = 0;
        for (int b = 0; b < nchunks; ++b) {
            int t = bsum[b];
            bsum[b] = carry;
            carry += t;
        }
        off[N_NODES] = carry;
    }
}

__global__ void k_scan3(int* __restrict__ off, const int* __restrict__ bsum) {
    int i = blockIdx.x * blockDim.x + threadIdx.x;
    if (i < N_NODES) off[i] += bsum[i >> 10];
}

__global__ void k_place(const int* __restrict__ ei,
                        const int* __restrict__ off,
                        const int* __restrict__ eslot,
                        int* __restrict__ csr) {
    int e = blockIdx.x * blockDim.x + threadIdx.x;
    if (e >= N_EDGES) return;
    int d = ei[N_EDGES + e];
    __builtin_nontemporal_store(ei[e], &csr[off[d] + eslot[e]]);
}

// ---------------------------------------------------------------------------
// x = node_embed @ W_in + b_in; writes fp32 h and bf16 shadow hb
__global__ __launch_bounds__(256) void k_input(const float* __restrict__ ne,
                                               const float* __restrict__ W_in,
                                               const float* __restrict__ b_in,
                                               float* __restrict__ h,
                                               ushort_t* __restrict__ hb) {
    __shared__ float sE[LNB][D_IN];            // 16 KB
    int tid = threadIdx.x;
    int j = tid & 63, w = tid >> 6;
    int nodeBase = blockIdx.x * LNB;
    {
        const float4* g = (const float4*)(ne + (size_t)nodeBase * D_IN);
        float4* l = (float4*)&sE[0][0];
        for (int i = tid; i < LNB * D_IN / 4; i += 256) l[i] = g[i];
    }
    __syncthreads();
    float acc[LR];
#pragma unroll
    for (int r = 0; r < LR; ++r) acc[r] = 0.0f;
#pragma unroll 4
    for (int k = 0; k < D_IN; ++k) {
        float wv = W_in[k * HID + j];
#pragma unroll
        for (int r = 0; r < LR; ++r)
            acc[r] = fmaf(sE[w * LR + r][k], wv, acc[r]);
    }
    float b = b_in[j];
#pragma unroll
    for (int r = 0; r < LR; ++r) {
        int n = nodeBase + w * LR + r;
        float v = acc[r] + b;
        h[(size_t)n * HID + j] = v;
        hb[(size_t)n * HID + j] = f2bf(v);
    }
}

// ---------------------------------------------------------------------------
// CSR gather over bf16 rows: one wave per node, 2 neighbor rows per wave-load.
// lane = (half = lane>>5, c = lane&31); each lane accumulates features 2c,2c+1
// of neighbors at positions i+half; final shfl_xor(32) combines halves.
__global__ __launch_bounds__(256) void k_gather(const int* __restrict__ off,
                                                const int* __restrict__ csr,
                                                const ushort_t* __restrict__ hb,
                                                float* __restrict__ agg) {
    int t = blockIdx.x * blockDim.x + threadIdx.x;
    int n = t >> 6;
    int lane = t & 63;
    int half = lane >> 5, c = lane & 31;
    int beg = off[n], end = off[n + 1];
    float a0 = 0.f, a1 = 0.f;
#pragma unroll 4
    for (int i = beg; i < end; i += 2) {
        int idx = i + half;
        if (idx < end) {
            int s = csr[idx];
            uint_t v = *(const uint_t*)(hb + (size_t)s * HID + c * 2);
            a0 += __uint_as_float(v << 16);
            a1 += __uint_as_float(v & 0xffff0000u);
        }
    }
    a0 += __shfl_xor(a0, 32);
    a1 += __shfl_xor(a1, 32);
    if (half == 0) {
        float2 t2; t2.x = a0; t2.y = a1;
        *(float2*)(agg + (size_t)n * HID + c * 2) = t2;
    }
}

// ---------------------------------------------------------------------------
// GRU update (in-place on h; each block touches only its own 32 rows).
// Writes fp32 h and bf16 shadow hb for the next layer's gather.
__global__ __launch_bounds__(256) void k_gru(const float* __restrict__ agg,
                                             float* __restrict__ h,
                                             ushort_t* __restrict__ hb,
                                             const float* __restrict__ W4f,
                                             const float* __restrict__ b_ih,
                                             const float* __restrict__ b_hh) {
    __shared__ float sA[LNB][HID];             // 8 KB
    __shared__ float sH[LNB][HID];             // 8 KB
    int tid = threadIdx.x;
    int j = tid & 63, w = tid >> 6;
    int nodeBase = blockIdx.x * LNB;
    {
        const float4* gA = (const float4*)(agg + (size_t)nodeBase * HID);
        const float4* gH = (const float4*)(h + (size_t)nodeBase * HID);
        float4* lA = (float4*)&sA[0][0];
        float4* lH = (float4*)&sH[0][0];
        lA[tid] = gA[tid]; lA[tid + 256] = gA[tid + 256];
        lH[tid] = gH[tid]; lH[tid + 256] = gH[tid + 256];
    }
    __syncthreads();

    float air[LR], aiz[LR], ain[LR], ahr[LR], ahz[LR], ahn[LR];
#pragma unroll
    for (int r = 0; r < LR; ++r) {
        air[r] = 0.f; aiz[r] = 0.f; ain[r] = 0.f;
        ahr[r] = 0.f; ahz[r] = 0.f; ahn[r] = 0.f;
    }
    const float4* W = (const float4*)W4f;
    for (int k4 = 0; k4 < 16; ++k4) {
        float4 wir = W[(k4 * 6 + 0) * 64 + j];
        float4 wiz = W[(k4 * 6 + 1) * 64 + j];
        float4 win = W[(k4 * 6 + 2) * 64 + j];
        float4 whr = W[(k4 * 6 + 3) * 64 + j];
        float4 whz = W[(k4 * 6 + 4) * 64 + j];
        float4 whn = W[(k4 * 6 + 5) * 64 + j];
#pragma unroll
        for (int r = 0; r < LR; ++r) {
            float4 a4 = *(const float4*)&sA[w * LR + r][k4 * 4];
            float4 h4 = *(const float4*)&sH[w * LR + r][k4 * 4];
            air[r] = fmaf(a4.x, wir.x, air[r]); air[r] = fmaf(a4.y, wir.y, air[r]);
            air[r] = fmaf(a4.z, wir.z, air[r]); air[r] = fmaf(a4.w, wir.w, air[r]);
            aiz[r] = fmaf(a4.x, wiz.x, aiz[r]); aiz[r] = fmaf(a4.y, wiz.y, aiz[r]);
            aiz[r] = fmaf(a4.z, wiz.z, aiz[r]); aiz[r] = fmaf(a4.w, wiz.w, aiz[r]);
            ain[r] = fmaf(a4.x, win.x, ain[r]); ain[r] = fmaf(a4.y, win.y, ain[r]);
            ain[r] = fmaf(a4.z, win.z, ain[r]); ain[r] = fmaf(a4.w, win.w, ain[r]);
            ahr[r] = fmaf(h4.x, whr.x, ahr[r]); ahr[r] = fmaf(h4.y, whr.y, ahr[r]);
            ahr[r] = fmaf(h4.z, whr.z, ahr[r]); ahr[r] = fmaf(h4.w, whr.w, ahr[r]);
            ahz[r] = fmaf(h4.x, whz.x, ahz[r]); ahz[r] = fmaf(h4.y, whz.y, ahz[r]);
            ahz[r] = fmaf(h4.z, whz.z, ahz[r]); ahz[r] = fmaf(h4.w, whz.w, ahz[r]);
            ahn[r] = fmaf(h4.x, whn.x, ahn[r]); ahn[r] = fmaf(h4.y, whn.y, ahn[r]);
            ahn[r] = fmaf(h4.z, whn.z, ahn[r]); ahn[r] = fmaf(h4.w, whn.w, ahn[r]);
        }
    }
    float bir = b_ih[j], biz = b_ih[64 + j], bin_ = b_ih[128 + j];
    float bhr = b_hh[j], bhz = b_hh[64 + j], bhn = b_hh[128 + j];
#pragma unroll
    for (int r = 0; r < LR; ++r) {
        int nn = w * LR + r;
        float rr = fast_sigmoid((air[r] + bir) + (ahr[r] + bhr));
        float zz = fast_sigmoid((aiz[r] + biz) + (ahz[r] + bhz));
        float nv = fast_tanh((ain[r] + bin_) + rr * (ahn[r] + bhn));
        float hold = sH[nn][j];
        float v = (1.0f - zz) * nv + zz * hold;
        size_t idx = (size_t)(nodeBase + nn) * HID + j;
        h[idx] = v;
        hb[idx] = f2bf(v);
    }
}

// ---------------------------------------------------------------------------
#define POOL_NPW 64
__global__ void k_pool(const float* __restrict__ h,
                       const int* __restrict__ batch,
                       float* __restrict__ sums,
                       float* __restrict__ cntf) {
    int wid = (blockIdx.x * blockDim.x + threadIdx.x) >> 6;
    int j = threadIdx.x & 63;
    int base = wid * POOL_NPW;
    if (base >= N_NODES) return;
    int end = base + POOL_NPW;
    if (end > N_NODES) end = N_NODES;
    float acc = 0.f, c = 0.f;
    int curg = batch[base];
    for (int n = base; n < end; ++n) {
        int g = batch[n];
        if (g != curg) {
            atomicAdd(&sums[(size_t)curg * HID + j], acc);
            if (j == 0) atomicAdd(&cntf[curg], c);
            acc = 0.f; c = 0.f; curg = g;
        }
        acc += h[(size_t)n * HID + j];
        c += 1.f;
    }
    atomicAdd(&sums[(size_t)curg * HID + j], acc);
    if (j == 0) atomicAdd(&cntf[curg], c);
}

__global__ void k_out(const float* __restrict__ sums,
                      const float* __restrict__ cntf,
                      const float* __restrict__ W_out,
                      const float* __restrict__ b_out,
                      float* __restrict__ out) {
    int t = blockIdx.x * blockDim.x + threadIdx.x;
    if (t >= N_GRAPHS * D_OUT) return;
    int g = t / D_OUT, o = t % D_OUT;
    float inv_c = __builtin_amdgcn_rcpf(fmaxf(cntf[g], 1.0f));
    float acc = 0.0f;
#pragma unroll
    for (int k = 0; k < HID; ++k)
        acc = fmaf(sums[g * HID + k], W_out[k * D_OUT + o], acc);
    out[t] = acc * inv_c + b_out[o];
}

// ---------------------------------------------------------------------------
static inline char* align256(char* p) {
    return (char*)(((uintptr_t)p + 255) & ~(uintptr_t)255);
}

extern "C" void kernel_launch(void* const* d_in, const int* in_sizes, int n_in,
                              void* d_out, int out_size, void* d_ws, size_t ws_size,
                              hipStream_t stream) {
    const float* node_embed = (const float*)d_in[0];
    const int*   edge_index = (const int*)  d_in[1];
    const int*   batch      = (const int*)  d_in[2];
    const float* W_in       = (const float*)d_in[3];
    const float* b_in       = (const float*)d_in[4];
    const float* ggnn_w     = (const float*)d_in[5];
    const float* gru_w_ih   = (const float*)d_in[6];
    const float* gru_w_hh   = (const float*)d_in[7];
    const float* gru_b_ih   = (const float*)d_in[8];
    const float* gru_b_hh   = (const float*)d_in[9];
    const float* W_out      = (const float*)d_in[10];
    const float* b_out      = (const float*)d_in[11];
    float* out = (float*)d_out;

    char* p = (char*)d_ws;
    float*    h     = (float*)p;    p = align256(p + (size_t)N_NODES * HID * sizeof(float));
    ushort_t* hb    = (ushort_t*)p; p = align256(p + (size_t)N_NODES * HID * sizeof(ushort_t));
    float*    agg   = (float*)p;    p = align256(p + (size_t)N_NODES * HID * sizeof(float));
    int*      csr   = (int*)p;      p = align256(p + (size_t)N_EDGES * sizeof(int));
    int*      eslot = (int*)p;      p = align256(p + (size_t)N_EDGES * sizeof(int));
    int*      off   = (int*)p;      p = align256(p + (size_t)(N_NODES + 1) * sizeof(int));
    int*      deg   = (int*)p;      p = align256(p + (size_t)N_NODES * sizeof(int));
    int*      bsum  = (int*)p;      p = align256(p + 256 * sizeof(int));
    float*    W4    = (float*)p;    p = align256(p + (size_t)N_LAYERS * 16 * 6 * 64 * 4 * sizeof(float));
    float*    sums  = (float*)p;
    float*    cntf  = (float*)(p + (size_t)N_GRAPHS * HID * sizeof(float));

    const int BLK = 256;
    const int nchunks = (N_NODES + SCHUNK - 1) / SCHUNK;

    k_prep<<<(N_LAYERS * 16 * 6 * 64 * 4 + BLK - 1) / BLK, BLK, 0, stream>>>(
        ggnn_w, gru_w_ih, gru_w_hh, W4);

    hipMemsetAsync(deg, 0, (size_t)N_NODES * sizeof(int), stream);
    k_hist<<<(N_EDGES + BLK - 1) / BLK, BLK, 0, stream>>>(edge_index, deg, eslot);
    k_scan1<<<nchunks, SCHUNK, 0, stream>>>(deg, off, bsum);
    k_scan2<<<1, 64, 0, stream>>>(bsum, off, nchunks);
    k_scan3<<<(N_NODES + BLK - 1) / BLK, BLK, 0, stream>>>(off, bsum);
    k_place<<<(N_EDGES + BLK - 1) / BLK, BLK, 0, stream>>>(edge_index, off, eslot, csr);

    k_input<<<N_NODES / LNB, BLK, 0, stream>>>(node_embed, W_in, b_in, h, hb);

    for (int l = 0; l < N_LAYERS; ++l) {
        k_gather<<<N_NODES * 64 / BLK, BLK, 0, stream>>>(off, csr, hb, agg);
        k_gru<<<N_NODES / LNB, BLK, 0, stream>>>(
            agg, h, hb, W4 + (size_t)l * 16 * 6 * 64 * 4, gru_b_ih, gru_b_hh);
    }

    hipMemsetAsync(sums, 0, (size_t)N_GRAPHS * (HID + 1) * sizeof(float), stream);
    {
        int waves = (N_NODES + POOL_NPW - 1) / POOL_NPW;
        int threads = waves * 64;
        k_pool<<<(threads + BLK - 1) / BLK, BLK, 0, stream>>>(h, batch, sums, cntf);
    }
    k_out<<<(N_GRAPHS * D_OUT + BLK - 1) / BLK, BLK, 0, stream>>>(sums, cntf, W_out, b_out, out);
}

// Round 5
// 738.410 us; speedup vs baseline: 1.8702x; 1.5283x over previous
//
#include <hip/hip_runtime.h>

#define N_NODES 100000
#define N_EDGES 1600000
#define D_IN 128
#define HID 64
#define N_LAYERS 5
#define D_OUT 32
#define N_GRAPHS 1000

#define LNB 32            // nodes per block in k_input (4 waves x 8)
#define LR 8              // nodes per thread in k_input

typedef unsigned short ushort_t;
typedef unsigned int uint_t;
typedef __attribute__((ext_vector_type(8))) short short8;   // 8 bf16 (4 VGPRs)
typedef __attribute__((ext_vector_type(4))) float f32x4;    // MFMA accumulator

#define MFMA(a, b, c) __builtin_amdgcn_mfma_f32_16x16x32_bf16((a), (b), (c), 0, 0, 0)

// per-layer stride of the prepped weight fragment arrays (in shorts)
#define WSTRIDE (24 * 2 * 64 * 8)

__device__ __forceinline__ float fast_sigmoid(float x) {
    return __builtin_amdgcn_rcpf(1.0f + __expf(-x));
}
__device__ __forceinline__ float fast_tanh(float x) {
    return 1.0f - 2.0f * __builtin_amdgcn_rcpf(1.0f + __expf(2.0f * x));
}
// fp32 -> bf16 round-to-nearest-even
__device__ __forceinline__ ushort_t f2bf(float f) {
    uint_t u = __float_as_uint(f);
    return (ushort_t)((u + 0x7fffu + ((u >> 16) & 1u)) >> 16);
}
// load 8 consecutive floats, split each into bf16 hi + bf16 lo
__device__ __forceinline__ void split8(const float* p, short8& hi, short8& lo) {
    float4 u0 = *(const float4*)p;
    float4 u1 = *(const float4*)(p + 4);
#define SPL(ii, fv) { float f_ = (fv); ushort_t h_ = f2bf(f_); hi[ii] = (short)h_;          \
                      float r_ = f_ - __uint_as_float(((uint_t)h_) << 16); lo[ii] = (short)f2bf(r_); }
    SPL(0, u0.x) SPL(1, u0.y) SPL(2, u0.z) SPL(3, u0.w)
    SPL(4, u1.x) SPL(5, u1.y) SPL(6, u1.z) SPL(7, u1.w)
#undef SPL
}

// ---------------------------------------------------------------------------
// Weight prep: emit bf16 hi/lo MFMA B-fragments.
// Combined B matrix [k=64][col=384]:
//   col<192 : Wc[k][col]   = sum_q ggnn_w[l][k][q] * w_ih[col][q]   (input side)
//   col>=192: w_hh[col-192][k]                                       (hidden side)
// Fragment layout: idx = ((((lay*24+t)*2+s)*64+lane)*8+i,
//   k = s*32 + (lane>>4)*8 + i,  col = t*16 + (lane&15).
__global__ void k_prep(const float* __restrict__ ggnn_w,
                       const float* __restrict__ w_ih,
                       const float* __restrict__ w_hh,
                       short* __restrict__ Whi,
                       short* __restrict__ Wlo) {
    int t = blockIdx.x * blockDim.x + threadIdx.x;
    if (t >= N_LAYERS * WSTRIDE) return;
    int i    = t & 7;
    int lane = (t >> 3) & 63;
    int s    = (t >> 9) & 1;
    int tt   = (t >> 10) % 24;
    int lay  = (t >> 10) / 24;
    int k    = s * 32 + (lane >> 4) * 8 + i;
    int col  = tt * 16 + (lane & 15);
    float val;
    if (col < 192) {
        const float* wl = ggnn_w + ((size_t)lay * HID + k) * HID;
        const float* wi = w_ih + (size_t)col * HID;
        float acc = 0.0f;
#pragma unroll 8
        for (int q = 0; q < HID; ++q) acc = fmaf(wl[q], wi[q], acc);
        val = acc;
    } else {
        val = w_hh[(size_t)(col - 192) * HID + k];
    }
    ushort_t h_ = f2bf(val);
    float r_ = val - __uint_as_float(((uint_t)h_) << 16);
    Whi[t] = (short)h_;
    Wlo[t] = (short)f2bf(r_);
}

// ---------------------------------------------------------------------------
// CSR build
__global__ void k_hist(const int* __restrict__ ei,
                       int* __restrict__ deg,
                       int* __restrict__ eslot) {
    int e = blockIdx.x * blockDim.x + threadIdx.x;
    if (e >= N_EDGES) return;
    eslot[e] = atomicAdd(&deg[ei[N_EDGES + e]], 1);
}

#define SCHUNK 1024
__global__ __launch_bounds__(1024) void k_scan1(const int* __restrict__ deg,
                                                int* __restrict__ off,
                                                int* __restrict__ bsum) {
    __shared__ int buf[SCHUNK];
    int tid = threadIdx.x;
    int i = blockIdx.x * SCHUNK + tid;
    int v = (i < N_NODES) ? deg[i] : 0;
    buf[tid] = v;
    __syncthreads();
    for (int s = 1; s < SCHUNK; s <<= 1) {
        int a = (tid >= s) ? buf[tid - s] : 0;
        __syncthreads();
        buf[tid] += a;
        __syncthreads();
    }
    if (i < N_NODES) off[i] = buf[tid] - v;
    if (tid == SCHUNK - 1) bsum[blockIdx.x] = buf[tid];
}

__global__ void k_scan2(int* __restrict__ bsum, int* __restrict__ off, int nchunks) {
    if (blockIdx.x == 0 && threadIdx.x == 0) {
        int carry = 0;
        for (int b = 0; b < nchunks; ++b) {
            int t = bsum[b];
            bsum[b] = carry;
            carry += t;
        }
        off[N_NODES] = carry;
    }
}

__global__ void k_scan3(int* __restrict__ off, const int* __restrict__ bsum) {
    int i = blockIdx.x * blockDim.x + threadIdx.x;
    if (i < N_NODES) off[i] += bsum[i >> 10];
}

__global__ void k_place(const int* __restrict__ ei,
                        const int* __restrict__ off,
                        const int* __restrict__ eslot,
                        int* __restrict__ csr) {
    int e = blockIdx.x * blockDim.x + threadIdx.x;
    if (e >= N_EDGES) return;
    int d = ei[N_EDGES + e];
    __builtin_nontemporal_store(ei[e], &csr[off[d] + eslot[e]]);
}

// ---------------------------------------------------------------------------
// x = node_embed @ W_in + b_in; writes fp32 h and bf16 shadow hb
__global__ __launch_bounds__(256) void k_input(const float* __restrict__ ne,
                                               const float* __restrict__ W_in,
                                               const float* __restrict__ b_in,
                                               float* __restrict__ h,
                                               ushort_t* __restrict__ hb) {
    __shared__ float sE[LNB][D_IN];            // 16 KB
    int tid = threadIdx.x;
    int j = tid & 63, w = tid >> 6;
    int nodeBase = blockIdx.x * LNB;
    {
        const float4* g = (const float4*)(ne + (size_t)nodeBase * D_IN);
        float4* l = (float4*)&sE[0][0];
        for (int i = tid; i < LNB * D_IN / 4; i += 256) l[i] = g[i];
    }
    __syncthreads();
    float acc[LR];
#pragma unroll
    for (int r = 0; r < LR; ++r) acc[r] = 0.0f;
#pragma unroll 4
    for (int k = 0; k < D_IN; ++k) {
        float wv = W_in[k * HID + j];
#pragma unroll
        for (int r = 0; r < LR; ++r)
            acc[r] = fmaf(sE[w * LR + r][k], wv, acc[r]);
    }
    float b = b_in[j];
#pragma unroll
    for (int r = 0; r < LR; ++r) {
        int n = nodeBase + w * LR + r;
        float v = acc[r] + b;
        h[(size_t)n * HID + j] = v;
        hb[(size_t)n * HID + j] = f2bf(v);
    }
}

// ---------------------------------------------------------------------------
// CSR gather over bf16 rows: one wave per node, 4 neighbor rows in flight.
// lane = (q = lane>>4, c = lane&15); 16 lanes x uint2 (8B) = one full 128B row.
__global__ __launch_bounds__(256) void k_gather(const int* __restrict__ off,
                                                const int* __restrict__ csr,
                                                const ushort_t* __restrict__ hb,
                                                float* __restrict__ agg) {
    int t = blockIdx.x * blockDim.x + threadIdx.x;
    int n = t >> 6;
    int lane = t & 63;
    int q = lane >> 4, c = lane & 15;
    int beg = off[n], end = off[n + 1];
    float a0 = 0.f, a1 = 0.f, a2 = 0.f, a3 = 0.f;
    for (int i = beg; i < end; i += 4) {
        int idx = i + q;
        int sidx = csr[min(idx, end - 1)];
        float msk = (idx < end) ? 1.0f : 0.0f;
        uint2 v = *(const uint2*)(hb + (size_t)sidx * HID + c * 4);
        a0 = fmaf(msk, __uint_as_float(v.x << 16), a0);
        a1 = fmaf(msk, __uint_as_float(v.x & 0xffff0000u), a1);
        a2 = fmaf(msk, __uint_as_float(v.y << 16), a2);
        a3 = fmaf(msk, __uint_as_float(v.y & 0xffff0000u), a3);
    }
    a0 += __shfl_xor(a0, 16); a1 += __shfl_xor(a1, 16);
    a2 += __shfl_xor(a2, 16); a3 += __shfl_xor(a3, 16);
    a0 += __shfl_xor(a0, 32); a1 += __shfl_xor(a1, 32);
    a2 += __shfl_xor(a2, 32); a3 += __shfl_xor(a3, 32);
    if (q == 0) {
        float4 t4; t4.x = a0; t4.y = a1; t4.z = a2; t4.w = a3;
        *(float4*)(agg + (size_t)n * HID + c * 4) = t4;
    }
}

// ---------------------------------------------------------------------------
// MFMA GRU: per wave 16 nodes x 384 gate outputs.
//   gates = [agg | h] @ B  (B prepped: cols 0..191 input side, 192..383 hidden)
// hi/lo bf16 split on A and B: Ah*Bh + Al*Bh + Ah*Bl  (residual ~2^-18).
// D layout (HW-verified): col = lane&15, row = (lane>>4)*4 + reg -> all 6 gate
// values for a (node,j) land in the same lane; elementwise GRU is lane-local.
__global__ __launch_bounds__(256) void k_gru(const float* __restrict__ agg,
                                             float* __restrict__ h,
                                             ushort_t* __restrict__ hb,
                                             const short* __restrict__ Whi,
                                             const short* __restrict__ Wlo,
                                             const float* __restrict__ b_ih,
                                             const float* __restrict__ b_hh) {
    int tid = threadIdx.x;
    int wv = tid >> 6, l = tid & 63;
    int q = l >> 4, c = l & 15;
    int nodeBase = blockIdx.x * 64 + wv * 16;

    // ---- A fragments: row = lane&15, k = s*32 + q*8 + i ----
    int anode = nodeBase + c;
    int acl = (anode < N_NODES) ? anode : (N_NODES - 1);
    const float* arow = agg + (size_t)acl * HID;
    const float* hrow = h + (size_t)acl * HID;
    short8 Ag_hi[2], Ag_lo[2], Ah_hi[2], Ah_lo[2];
#pragma unroll
    for (int s = 0; s < 2; ++s) {
        int k0 = s * 32 + q * 8;
        split8(arow + k0, Ag_hi[s], Ag_lo[s]);
        split8(hrow + k0, Ah_hi[s], Ah_lo[s]);
    }

    f32x4 acc[24];
    const f32x4 zero = {0.f, 0.f, 0.f, 0.f};
#pragma unroll
    for (int t = 0; t < 24; ++t) acc[t] = zero;

    const short8* BH = ((const short8*)Whi) + l;
    const short8* BL = ((const short8*)Wlo) + l;
#pragma unroll
    for (int t = 0; t < 24; ++t) {
        short8 b0h = BH[(t * 2 + 0) * 64];
        short8 b1h = BH[(t * 2 + 1) * 64];
        short8 b0l = BL[(t * 2 + 0) * 64];
        short8 b1l = BL[(t * 2 + 1) * 64];
        short8 a0h = (t < 12) ? Ag_hi[0] : Ah_hi[0];
        short8 a0l = (t < 12) ? Ag_lo[0] : Ah_lo[0];
        short8 a1h = (t < 12) ? Ag_hi[1] : Ah_hi[1];
        short8 a1l = (t < 12) ? Ag_lo[1] : Ah_lo[1];
        acc[t] = MFMA(a0h, b0h, acc[t]);
        acc[t] = MFMA(a0l, b0h, acc[t]);
        acc[t] = MFMA(a0h, b0l, acc[t]);
        acc[t] = MFMA(a1h, b1h, acc[t]);
        acc[t] = MFMA(a1l, b1h, acc[t]);
        acc[t] = MFMA(a1h, b1l, acc[t]);
    }

    // ---- elementwise GRU, lane-local ----
    // tile t = 4g + jb covers gate g at j = jb*16 + c; node m = nodeBase + q*4 + i
#pragma unroll
    for (int jb = 0; jb < 4; ++jb) {
        int j = jb * 16 + c;
        float br  = b_ih[j] + b_hh[j];
        float bz  = b_ih[64 + j] + b_hh[64 + j];
        float bin = b_ih[128 + j];
        float bhn = b_hh[128 + j];
#pragma unroll
        for (int i = 0; i < 4; ++i) {
            int m = nodeBase + q * 4 + i;
            if (m < N_NODES) {
                float ir = acc[jb][i],      iz = acc[4 + jb][i],  inn = acc[8 + jb][i];
                float hr = acc[12 + jb][i], hz = acc[16 + jb][i], hn = acc[20 + jb][i];
                float rr = fast_sigmoid(ir + hr + br);
                float zz = fast_sigmoid(iz + hz + bz);
                float nv = fast_tanh((inn + bin) + rr * (hn + bhn));
                size_t idx = (size_t)m * HID + j;
                float hold = h[idx];
                float v = (1.0f - zz) * nv + zz * hold;
                h[idx] = v;
                hb[idx] = f2bf(v);
            }
        }
    }
}

// ---------------------------------------------------------------------------
#define POOL_NPW 64
__global__ void k_pool(const float* __restrict__ h,
                       const int* __restrict__ batch,
                       float* __restrict__ sums,
                       float* __restrict__ cntf) {
    int wid = (blockIdx.x * blockDim.x + threadIdx.x) >> 6;
    int j = threadIdx.x & 63;
    int base = wid * POOL_NPW;
    if (base >= N_NODES) return;
    int end = base + POOL_NPW;
    if (end > N_NODES) end = N_NODES;
    float acc = 0.f, c = 0.f;
    int curg = batch[base];
    for (int n = base; n < end; ++n) {
        int g = batch[n];
        if (g != curg) {
            atomicAdd(&sums[(size_t)curg * HID + j], acc);
            if (j == 0) atomicAdd(&cntf[curg], c);
            acc = 0.f; c = 0.f; curg = g;
        }
        acc += h[(size_t)n * HID + j];
        c += 1.f;
    }
    atomicAdd(&sums[(size_t)curg * HID + j], acc);
    if (j == 0) atomicAdd(&cntf[curg], c);
}

__global__ void k_out(const float* __restrict__ sums,
                      const float* __restrict__ cntf,
                      const float* __restrict__ W_out,
                      const float* __restrict__ b_out,
                      float* __restrict__ out) {
    int t = blockIdx.x * blockDim.x + threadIdx.x;
    if (t >= N_GRAPHS * D_OUT) return;
    int g = t / D_OUT, o = t % D_OUT;
    float inv_c = __builtin_amdgcn_rcpf(fmaxf(cntf[g], 1.0f));
    float acc = 0.0f;
#pragma unroll
    for (int k = 0; k < HID; ++k)
        acc = fmaf(sums[g * HID + k], W_out[k * D_OUT + o], acc);
    out[t] = acc * inv_c + b_out[o];
}

// ---------------------------------------------------------------------------
static inline char* align256(char* p) {
    return (char*)(((uintptr_t)p + 255) & ~(uintptr_t)255);
}

extern "C" void kernel_launch(void* const* d_in, const int* in_sizes, int n_in,
                              void* d_out, int out_size, void* d_ws, size_t ws_size,
                              hipStream_t stream) {
    const float* node_embed = (const float*)d_in[0];
    const int*   edge_index = (const int*)  d_in[1];
    const int*   batch      = (const int*)  d_in[2];
    const float* W_in       = (const float*)d_in[3];
    const float* b_in       = (const float*)d_in[4];
    const float* ggnn_w     = (const float*)d_in[5];
    const float* gru_w_ih   = (const float*)d_in[6];
    const float* gru_w_hh   = (const float*)d_in[7];
    const float* gru_b_ih   = (const float*)d_in[8];
    const float* gru_b_hh   = (const float*)d_in[9];
    const float* W_out      = (const float*)d_in[10];
    const float* b_out      = (const float*)d_in[11];
    float* out = (float*)d_out;

    char* p = (char*)d_ws;
    float*    h     = (float*)p;    p = align256(p + (size_t)N_NODES * HID * sizeof(float));
    ushort_t* hb    = (ushort_t*)p; p = align256(p + (size_t)N_NODES * HID * sizeof(ushort_t));
    float*    agg   = (float*)p;    p = align256(p + (size_t)N_NODES * HID * sizeof(float));
    int*      csr   = (int*)p;      p = align256(p + (size_t)N_EDGES * sizeof(int));
    int*      eslot = (int*)p;      p = align256(p + (size_t)N_EDGES * sizeof(int));
    int*      off   = (int*)p;      p = align256(p + (size_t)(N_NODES + 1) * sizeof(int));
    int*      deg   = (int*)p;      p = align256(p + (size_t)N_NODES * sizeof(int));
    int*      bsum  = (int*)p;      p = align256(p + 256 * sizeof(int));
    short*    Whi   = (short*)p;    p = align256(p + (size_t)N_LAYERS * WSTRIDE * sizeof(short));
    short*    Wlo   = (short*)p;    p = align256(p + (size_t)N_LAYERS * WSTRIDE * sizeof(short));
    float*    sums  = (float*)p;
    float*    cntf  = (float*)(p + (size_t)N_GRAPHS * HID * sizeof(float));

    const int BLK = 256;
    const int nchunks = (N_NODES + SCHUNK - 1) / SCHUNK;

    k_prep<<<(N_LAYERS * WSTRIDE + BLK - 1) / BLK, BLK, 0, stream>>>(
        ggnn_w, gru_w_ih, gru_w_hh, Whi, Wlo);

    hipMemsetAsync(deg, 0, (size_t)N_NODES * sizeof(int), stream);
    k_hist<<<(N_EDGES + BLK - 1) / BLK, BLK, 0, stream>>>(edge_index, deg, eslot);
    k_scan1<<<nchunks, SCHUNK, 0, stream>>>(deg, off, bsum);
    k_scan2<<<1, 64, 0, stream>>>(bsum, off, nchunks);
    k_scan3<<<(N_NODES + BLK - 1) / BLK, BLK, 0, stream>>>(off, bsum);
    k_place<<<(N_EDGES + BLK - 1) / BLK, BLK, 0, stream>>>(edge_index, off, eslot, csr);

    k_input<<<N_NODES / LNB, BLK, 0, stream>>>(node_embed, W_in, b_in, h, hb);

    for (int l = 0; l < N_LAYERS; ++l) {
        k_gather<<<N_NODES * 64 / BLK, BLK, 0, stream>>>(off, csr, hb, agg);
        k_gru<<<(N_NODES + 63) / 64, BLK, 0, stream>>>(
            agg, h, hb, Whi + (size_t)l * WSTRIDE, Wlo + (size_t)l * WSTRIDE,
            gru_b_ih, gru_b_hh);
    }

    hipMemsetAsync(sums, 0, (size_t)N_GRAPHS * (HID + 1) * sizeof(float), stream);
    {
        int waves = (N_NODES + POOL_NPW - 1) / POOL_NPW;
        int threads = waves * 64;
        k_pool<<<(threads + BLK - 1) / BLK, BLK, 0, stream>>>(h, batch, sums, cntf);
    }
    k_out<<<(N_GRAPHS * D_OUT + BLK - 1) / BLK, BLK, 0, stream>>>(sums, cntf, W_out, b_out, out);
}

// Round 6
// 606.604 us; speedup vs baseline: 2.2766x; 1.2173x over previous
//
#include <hip/hip_runtime.h>

#define N_NODES 100000
#define N_EDGES 1600000
#define D_IN 128
#define HID 64
#define N_LAYERS 5
#define D_OUT 32
#define N_GRAPHS 1000

#define LNB 32            // nodes per block in k_input (4 waves x 8)
#define LR 8              // nodes per thread in k_input
#define NSHARD 8          // histogram shards (XCD count)

typedef unsigned short ushort_t;
typedef unsigned int uint_t;
typedef __attribute__((ext_vector_type(8))) short short8;   // 8 bf16 (4 VGPRs)
typedef __attribute__((ext_vector_type(4))) float f32x4;    // MFMA accumulator

#define MFMA(a, b, c) __builtin_amdgcn_mfma_f32_16x16x32_bf16((a), (b), (c), 0, 0, 0)

// per-layer stride of the prepped weight fragment arrays (in shorts)
#define WSTRIDE (24 * 2 * 64 * 8)

__device__ __forceinline__ float fast_sigmoid(float x) {
    return __builtin_amdgcn_rcpf(1.0f + __expf(-x));
}
__device__ __forceinline__ float fast_tanh(float x) {
    return 1.0f - 2.0f * __builtin_amdgcn_rcpf(1.0f + __expf(2.0f * x));
}
// fp32 -> bf16 round-to-nearest-even
__device__ __forceinline__ ushort_t f2bf(float f) {
    uint_t u = __float_as_uint(f);
    return (ushort_t)((u + 0x7fffu + ((u >> 16) & 1u)) >> 16);
}
// load 8 consecutive floats, split each into bf16 hi + bf16 lo
__device__ __forceinline__ void split8(const float* p, short8& hi, short8& lo) {
    float4 u0 = *(const float4*)p;
    float4 u1 = *(const float4*)(p + 4);
#define SPL(ii, fv) { float f_ = (fv); ushort_t h_ = f2bf(f_); hi[ii] = (short)h_;          \
                      float r_ = f_ - __uint_as_float(((uint_t)h_) << 16); lo[ii] = (short)f2bf(r_); }
    SPL(0, u0.x) SPL(1, u0.y) SPL(2, u0.z) SPL(3, u0.w)
    SPL(4, u1.x) SPL(5, u1.y) SPL(6, u1.z) SPL(7, u1.w)
#undef SPL
}

// ---------------------------------------------------------------------------
// Weight prep: emit bf16 hi/lo MFMA B-fragments.
// Combined B matrix [k=64][col=384]:
//   col<192 : Wc[k][col]   = sum_q ggnn_w[l][k][q] * w_ih[col][q]   (input side)
//   col>=192: w_hh[col-192][k]                                       (hidden side)
// Fragment layout: idx = ((((lay*24+t)*2+s)*64+lane)*8+i,
//   k = s*32 + (lane>>4)*8 + i,  col = t*16 + (lane&15).
__global__ void k_prep(const float* __restrict__ ggnn_w,
                       const float* __restrict__ w_ih,
                       const float* __restrict__ w_hh,
                       short* __restrict__ Whi,
                       short* __restrict__ Wlo) {
    int t = blockIdx.x * blockDim.x + threadIdx.x;
    if (t >= N_LAYERS * WSTRIDE) return;
    int i    = t & 7;
    int lane = (t >> 3) & 63;
    int s    = (t >> 9) & 1;
    int tt   = (t >> 10) % 24;
    int lay  = (t >> 10) / 24;
    int k    = s * 32 + (lane >> 4) * 8 + i;
    int col  = tt * 16 + (lane & 15);
    float val;
    if (col < 192) {
        const float* wl = ggnn_w + ((size_t)lay * HID + k) * HID;
        const float* wi = w_ih + (size_t)col * HID;
        float acc = 0.0f;
#pragma unroll 8
        for (int q = 0; q < HID; ++q) acc = fmaf(wl[q], wi[q], acc);
        val = acc;
    } else {
        val = w_hh[(size_t)(col - 192) * HID + k];
    }
    ushort_t h_ = f2bf(val);
    float r_ = val - __uint_as_float(((uint_t)h_) << 16);
    Whi[t] = (short)h_;
    Wlo[t] = (short)f2bf(r_);
}

// ---------------------------------------------------------------------------
// CSR build — sharded histogram: shard = blockIdx&7 keeps each shard's lines
// on (heuristically) one XCD's L2, cutting cross-XCD line ping-pong.
__global__ void k_hist(const int* __restrict__ ei,
                       int* __restrict__ deg8,
                       int* __restrict__ eslot) {
    int e = blockIdx.x * blockDim.x + threadIdx.x;
    if (e >= N_EDGES) return;
    int s = blockIdx.x & (NSHARD - 1);
    eslot[e] = atomicAdd(&deg8[s * N_NODES + ei[N_EDGES + e]], 1);
}

#define SCHUNK 1024
// scan1: fold 8 shards -> total degree; convert deg8 in-place to shard-prefix.
__global__ __launch_bounds__(1024) void k_scan1(int* __restrict__ deg8,
                                                int* __restrict__ off,
                                                int* __restrict__ bsum) {
    __shared__ int buf[SCHUNK];
    int tid = threadIdx.x;
    int i = blockIdx.x * SCHUNK + tid;
    int tot = 0;
    if (i < N_NODES) {
        int pre[NSHARD];
#pragma unroll
        for (int s = 0; s < NSHARD; ++s) {
            pre[s] = tot;
            tot += deg8[s * N_NODES + i];
        }
#pragma unroll
        for (int s = 0; s < NSHARD; ++s) deg8[s * N_NODES + i] = pre[s];
    }
    buf[tid] = tot;
    __syncthreads();
    for (int s = 1; s < SCHUNK; s <<= 1) {
        int a = (tid >= s) ? buf[tid - s] : 0;
        __syncthreads();
        buf[tid] += a;
        __syncthreads();
    }
    if (i < N_NODES) off[i] = buf[tid] - tot;
    if (tid == SCHUNK - 1) bsum[blockIdx.x] = buf[tid];
}

__global__ void k_scan2(int* __restrict__ bsum, int* __restrict__ off, int nchunks) {
    if (blockIdx.x == 0 && threadIdx.x == 0) {
        int carry = 0;
        for (int b = 0; b < nchunks; ++b) {
            int t = bsum[b];
            bsum[b] = carry;
            carry += t;
        }
        off[N_NODES] = carry;
    }
}

__global__ void k_scan3(int* __restrict__ off, const int* __restrict__ bsum) {
    int i = blockIdx.x * blockDim.x + threadIdx.x;
    if (i < N_NODES) off[i] += bsum[i >> 10];
}

// place: pos = off[d] + shard_prefix[s][d] + slot_within_shard
// grid/block identical to k_hist so blockIdx&7 reproduces each edge's shard.
__global__ void k_place(const int* __restrict__ ei,
                        const int* __restrict__ off,
                        const int* __restrict__ deg8,
                        const int* __restrict__ eslot,
                        int* __restrict__ csr) {
    int e = blockIdx.x * blockDim.x + threadIdx.x;
    if (e >= N_EDGES) return;
    int s = blockIdx.x & (NSHARD - 1);
    int d = ei[N_EDGES + e];
    __builtin_nontemporal_store(ei[e], &csr[off[d] + deg8[s * N_NODES + d] + eslot[e]]);
}

// ---------------------------------------------------------------------------
// x = node_embed @ W_in + b_in; writes fp32 h and bf16 shadow hb
__global__ __launch_bounds__(256) void k_input(const float* __restrict__ ne,
                                               const float* __restrict__ W_in,
                                               const float* __restrict__ b_in,
                                               float* __restrict__ h,
                                               ushort_t* __restrict__ hb) {
    __shared__ float sE[LNB][D_IN];            // 16 KB
    int tid = threadIdx.x;
    int j = tid & 63, w = tid >> 6;
    int nodeBase = blockIdx.x * LNB;
    {
        const float4* g = (const float4*)(ne + (size_t)nodeBase * D_IN);
        float4* l = (float4*)&sE[0][0];
        for (int i = tid; i < LNB * D_IN / 4; i += 256) l[i] = g[i];
    }
    __syncthreads();
    float acc[LR];
#pragma unroll
    for (int r = 0; r < LR; ++r) acc[r] = 0.0f;
#pragma unroll 4
    for (int k = 0; k < D_IN; ++k) {
        float wv = W_in[k * HID + j];
#pragma unroll
        for (int r = 0; r < LR; ++r)
            acc[r] = fmaf(sE[w * LR + r][k], wv, acc[r]);
    }
    float b = b_in[j];
#pragma unroll
    for (int r = 0; r < LR; ++r) {
        int n = nodeBase + w * LR + r;
        float v = acc[r] + b;
        h[(size_t)n * HID + j] = v;
        hb[(size_t)n * HID + j] = f2bf(v);
    }
}

// ---------------------------------------------------------------------------
// CSR gather over bf16 rows: one wave per node, 8 neighbor rows in flight.
// lane = (q = lane>>3 neighbor slot, c = lane&7 16B chunk); 8 lanes x uint4
// = one full 128B row. Reduce across q via 3 shfl_xor steps.
__global__ __launch_bounds__(256) void k_gather(const int* __restrict__ off,
                                                const int* __restrict__ csr,
                                                const ushort_t* __restrict__ hb,
                                                float* __restrict__ agg) {
    int t = blockIdx.x * blockDim.x + threadIdx.x;
    int n = t >> 6;
    int lane = t & 63;
    int q = lane >> 3, c = lane & 7;
    int beg = off[n], end = off[n + 1];
    float a[8];
#pragma unroll
    for (int x = 0; x < 8; ++x) a[x] = 0.f;
#pragma unroll 2
    for (int i = beg; i < end; i += 8) {
        int idx = i + q;
        int sidx = csr[min(idx, end - 1)];
        float msk = (idx < end) ? 1.0f : 0.0f;
        uint4 v = *(const uint4*)(hb + (size_t)sidx * HID + c * 8);
        a[0] = fmaf(msk, __uint_as_float(v.x << 16), a[0]);
        a[1] = fmaf(msk, __uint_as_float(v.x & 0xffff0000u), a[1]);
        a[2] = fmaf(msk, __uint_as_float(v.y << 16), a[2]);
        a[3] = fmaf(msk, __uint_as_float(v.y & 0xffff0000u), a[3]);
        a[4] = fmaf(msk, __uint_as_float(v.z << 16), a[4]);
        a[5] = fmaf(msk, __uint_as_float(v.z & 0xffff0000u), a[5]);
        a[6] = fmaf(msk, __uint_as_float(v.w << 16), a[6]);
        a[7] = fmaf(msk, __uint_as_float(v.w & 0xffff0000u), a[7]);
    }
#pragma unroll
    for (int x = 0; x < 8; ++x) {
        a[x] += __shfl_xor(a[x], 8);
        a[x] += __shfl_xor(a[x], 16);
        a[x] += __shfl_xor(a[x], 32);
    }
    if (q == 0) {
        float4 lo4; lo4.x = a[0]; lo4.y = a[1]; lo4.z = a[2]; lo4.w = a[3];
        float4 hi4; hi4.x = a[4]; hi4.y = a[5]; hi4.z = a[6]; hi4.w = a[7];
        *(float4*)(agg + (size_t)n * HID + c * 8) = lo4;
        *(float4*)(agg + (size_t)n * HID + c * 8 + 4) = hi4;
    }
}

// ---------------------------------------------------------------------------
// MFMA GRU: per wave 16 nodes x 384 gate outputs.
//   gates = [agg | h] @ B  (B prepped: cols 0..191 input side, 192..383 hidden)
// hi/lo bf16 split: Ah*Bh + Al*Bh + Ah*Bl (residual ~2^-18).
// Whi staged in LDS (48 KB) so the block's 4 waves read it once from L2.
__global__ __launch_bounds__(256) void k_gru(const float* __restrict__ agg,
                                             float* __restrict__ h,
                                             ushort_t* __restrict__ hb,
                                             const short* __restrict__ Whi,
                                             const short* __restrict__ Wlo,
                                             const float* __restrict__ b_ih,
                                             const float* __restrict__ b_hh) {
    __shared__ short8 sW[24 * 2 * 64];         // 48 KB
    int tid = threadIdx.x;
    {
        const short8* gW = (const short8*)Whi;
#pragma unroll
        for (int i = 0; i < 12; ++i) sW[tid + i * 256] = gW[tid + i * 256];
    }
    int wv = tid >> 6, l = tid & 63;
    int q = l >> 4, c = l & 15;
    int nodeBase = blockIdx.x * 64 + wv * 16;

    // ---- A fragments: row = lane&15, k = s*32 + q*8 + i ----
    int anode = nodeBase + c;
    int acl = (anode < N_NODES) ? anode : (N_NODES - 1);
    const float* arow = agg + (size_t)acl * HID;
    const float* hrow = h + (size_t)acl * HID;
    short8 Ag_hi[2], Ag_lo[2], Ah_hi[2], Ah_lo[2];
#pragma unroll
    for (int s = 0; s < 2; ++s) {
        int k0 = s * 32 + q * 8;
        split8(arow + k0, Ag_hi[s], Ag_lo[s]);
        split8(hrow + k0, Ah_hi[s], Ah_lo[s]);
    }
    __syncthreads();

    f32x4 acc[24];
    const f32x4 zero = {0.f, 0.f, 0.f, 0.f};
#pragma unroll
    for (int t = 0; t < 24; ++t) acc[t] = zero;

    const short8* BH = sW + l;
    const short8* BL = ((const short8*)Wlo) + l;
#pragma unroll
    for (int t = 0; t < 24; ++t) {
        short8 b0h = BH[(t * 2 + 0) * 64];
        short8 b1h = BH[(t * 2 + 1) * 64];
        short8 b0l = BL[(t * 2 + 0) * 64];
        short8 b1l = BL[(t * 2 + 1) * 64];
        short8 a0h = (t < 12) ? Ag_hi[0] : Ah_hi[0];
        short8 a0l = (t < 12) ? Ag_lo[0] : Ah_lo[0];
        short8 a1h = (t < 12) ? Ag_hi[1] : Ah_hi[1];
        short8 a1l = (t < 12) ? Ag_lo[1] : Ah_lo[1];
        acc[t] = MFMA(a0h, b0h, acc[t]);
        acc[t] = MFMA(a0l, b0h, acc[t]);
        acc[t] = MFMA(a0h, b0l, acc[t]);
        acc[t] = MFMA(a1h, b1h, acc[t]);
        acc[t] = MFMA(a1l, b1h, acc[t]);
        acc[t] = MFMA(a1h, b1l, acc[t]);
    }

    // ---- elementwise GRU, lane-local ----
    // tile t = 4g + jb covers gate g at j = jb*16 + c; node m = nodeBase + q*4 + i
#pragma unroll
    for (int jb = 0; jb < 4; ++jb) {
        int j = jb * 16 + c;
        float br  = b_ih[j] + b_hh[j];
        float bz  = b_ih[64 + j] + b_hh[64 + j];
        float bin = b_ih[128 + j];
        float bhn = b_hh[128 + j];
#pragma unroll
        for (int i = 0; i < 4; ++i) {
            int m = nodeBase + q * 4 + i;
            if (m < N_NODES) {
                float ir = acc[jb][i],      iz = acc[4 + jb][i],  inn = acc[8 + jb][i];
                float hr = acc[12 + jb][i], hz = acc[16 + jb][i], hn = acc[20 + jb][i];
                float rr = fast_sigmoid(ir + hr + br);
                float zz = fast_sigmoid(iz + hz + bz);
                float nv = fast_tanh((inn + bin) + rr * (hn + bhn));
                size_t idx = (size_t)m * HID + j;
                float hold = h[idx];
                float v = (1.0f - zz) * nv + zz * hold;
                h[idx] = v;
                hb[idx] = f2bf(v);
            }
        }
    }
}

// ---------------------------------------------------------------------------
#define POOL_NPW 64
__global__ void k_pool(const float* __restrict__ h,
                       const int* __restrict__ batch,
                       float* __restrict__ sums,
                       float* __restrict__ cntf) {
    int wid = (blockIdx.x * blockDim.x + threadIdx.x) >> 6;
    int j = threadIdx.x & 63;
    int base = wid * POOL_NPW;
    if (base >= N_NODES) return;
    int end = base + POOL_NPW;
    if (end > N_NODES) end = N_NODES;
    float acc = 0.f, c = 0.f;
    int curg = batch[base];
    for (int n = base; n < end; ++n) {
        int g = batch[n];
        if (g != curg) {
            atomicAdd(&sums[(size_t)curg * HID + j], acc);
            if (j == 0) atomicAdd(&cntf[curg], c);
            acc = 0.f; c = 0.f; curg = g;
        }
        acc += h[(size_t)n * HID + j];
        c += 1.f;
    }
    atomicAdd(&sums[(size_t)curg * HID + j], acc);
    if (j == 0) atomicAdd(&cntf[curg], c);
}

__global__ void k_out(const float* __restrict__ sums,
                      const float* __restrict__ cntf,
                      const float* __restrict__ W_out,
                      const float* __restrict__ b_out,
                      float* __restrict__ out) {
    int t = blockIdx.x * blockDim.x + threadIdx.x;
    if (t >= N_GRAPHS * D_OUT) return;
    int g = t / D_OUT, o = t % D_OUT;
    float inv_c = __builtin_amdgcn_rcpf(fmaxf(cntf[g], 1.0f));
    float acc = 0.0f;
#pragma unroll
    for (int k = 0; k < HID; ++k)
        acc = fmaf(sums[g * HID + k], W_out[k * D_OUT + o], acc);
    out[t] = acc * inv_c + b_out[o];
}

// ---------------------------------------------------------------------------
static inline char* align256(char* p) {
    return (char*)(((uintptr_t)p + 255) & ~(uintptr_t)255);
}

extern "C" void kernel_launch(void* const* d_in, const int* in_sizes, int n_in,
                              void* d_out, int out_size, void* d_ws, size_t ws_size,
                              hipStream_t stream) {
    const float* node_embed = (const float*)d_in[0];
    const int*   edge_index = (const int*)  d_in[1];
    const int*   batch      = (const int*)  d_in[2];
    const float* W_in       = (const float*)d_in[3];
    const float* b_in       = (const float*)d_in[4];
    const float* ggnn_w     = (const float*)d_in[5];
    const float* gru_w_ih   = (const float*)d_in[6];
    const float* gru_w_hh   = (const float*)d_in[7];
    const float* gru_b_ih   = (const float*)d_in[8];
    const float* gru_b_hh   = (const float*)d_in[9];
    const float* W_out      = (const float*)d_in[10];
    const float* b_out      = (const float*)d_in[11];
    float* out = (float*)d_out;

    char* p = (char*)d_ws;
    float*    h     = (float*)p;    p = align256(p + (size_t)N_NODES * HID * sizeof(float));
    ushort_t* hb    = (ushort_t*)p; p = align256(p + (size_t)N_NODES * HID * sizeof(ushort_t));
    float*    agg   = (float*)p;    p = align256(p + (size_t)N_NODES * HID * sizeof(float));
    int*      csr   = (int*)p;      p = align256(p + (size_t)N_EDGES * sizeof(int));
    int*      eslot = (int*)p;      p = align256(p + (size_t)N_EDGES * sizeof(int));
    int*      off   = (int*)p;      p = align256(p + (size_t)(N_NODES + 1) * sizeof(int));
    int*      deg8  = (int*)p;      p = align256(p + (size_t)NSHARD * N_NODES * sizeof(int));
    int*      bsum  = (int*)p;      p = align256(p + 256 * sizeof(int));
    short*    Whi   = (short*)p;    p = align256(p + (size_t)N_LAYERS * WSTRIDE * sizeof(short));
    short*    Wlo   = (short*)p;    p = align256(p + (size_t)N_LAYERS * WSTRIDE * sizeof(short));
    float*    sums  = (float*)p;
    float*    cntf  = (float*)(p + (size_t)N_GRAPHS * HID * sizeof(float));

    const int BLK = 256;
    const int nchunks = (N_NODES + SCHUNK - 1) / SCHUNK;

    k_prep<<<(N_LAYERS * WSTRIDE + BLK - 1) / BLK, BLK, 0, stream>>>(
        ggnn_w, gru_w_ih, gru_w_hh, Whi, Wlo);

    hipMemsetAsync(deg8, 0, (size_t)NSHARD * N_NODES * sizeof(int), stream);
    k_hist<<<(N_EDGES + BLK - 1) / BLK, BLK, 0, stream>>>(edge_index, deg8, eslot);
    k_scan1<<<nchunks, SCHUNK, 0, stream>>>(deg8, off, bsum);
    k_scan2<<<1, 64, 0, stream>>>(bsum, off, nchunks);
    k_scan3<<<(N_NODES + BLK - 1) / BLK, BLK, 0, stream>>>(off, bsum);
    k_place<<<(N_EDGES + BLK - 1) / BLK, BLK, 0, stream>>>(edge_index, off, deg8, eslot, csr);

    k_input<<<N_NODES / LNB, BLK, 0, stream>>>(node_embed, W_in, b_in, h, hb);

    for (int l = 0; l < N_LAYERS; ++l) {
        k_gather<<<N_NODES * 64 / BLK, BLK, 0, stream>>>(off, csr, hb, agg);
        k_gru<<<(N_NODES + 63) / 64, BLK, 0, stream>>>(
            agg, h, hb, Whi + (size_t)l * WSTRIDE, Wlo + (size_t)l * WSTRIDE,
            gru_b_ih, gru_b_hh);
    }

    hipMemsetAsync(sums, 0, (size_t)N_GRAPHS * (HID + 1) * sizeof(float), stream);
    {
        int waves = (N_NODES + POOL_NPW - 1) / POOL_NPW;
        int threads = waves * 64;
        k_pool<<<(threads + BLK - 1) / BLK, BLK, 0, stream>>>(h, batch, sums, cntf);
    }
    k_out<<<(N_GRAPHS * D_OUT + BLK - 1) / BLK, BLK, 0, stream>>>(sums, cntf, W_out, b_out, out);
}